// Round 1
// baseline (891.802 us; speedup 1.0000x reference)
//
#include <hip/hip_runtime.h>
#include <math.h>

// Problem constants
#define Hs    128
#define G4    512          // 4*H
#define Mrows 32           // batch rows per block in main kernel
#define KP    40           // xh LDS row pitch (floats), 16B aligned rows
#define KOBS  162          // 128 (h) + 2 (o_t) + 32 (pooled)
#define KPRED 130          // 128 (h) + 2 (prev disp)
#define Bsz   16384
#define Tobs  8
#define NBR   64
#define EMB   32
#define PREDL 12

__device__ __forceinline__ float sigm(float x) { return 1.f / (1.f + expf(-x)); }

// ---------------------------------------------------------------------------
// Pack kernel: build Wt[KOBS][512] (k-major), column-permuted:
//   n = cg*8 + q, q in [0,8): gate = q>>1, e = q&1, j = gate*128 + 2*cg + e
//   k in [0,128)   : W_hh[j][k]
//   k in [128,130) : W_io[j][k-128]  = sum_m W_ih[j][m]     * W_in[m][k-128]
//   k in [130,162) : W_isp[j][k-130] = sum_m W_ih[j][128+m] * W_sp[m][k-130]
// ---------------------------------------------------------------------------
__global__ void pack_w_kernel(const float* __restrict__ W_ih, const float* __restrict__ W_hh,
                              const float* __restrict__ W_in, const float* __restrict__ W_sp,
                              float* __restrict__ Wt) {
  int gid = blockIdx.x * blockDim.x + threadIdx.x;
  if (gid >= KOBS * G4) return;
  int k = gid >> 9;
  int n = gid & 511;
  int cg = n >> 3, q = n & 7;
  int gate = q >> 1, e = q & 1;
  int j = gate * Hs + 2 * cg + e;
  float v;
  if (k < 128) {
    v = W_hh[j * Hs + k];
  } else if (k < 130) {
    int c = k - 128;
    float s = 0.f;
    for (int m = 0; m < 128; ++m) s += W_ih[j * 256 + m] * W_in[m * 2 + c];
    v = s;
  } else {
    int ee = k - 130;
    float s = 0.f;
    for (int m = 0; m < 128; ++m) s += W_ih[j * 256 + 128 + m] * W_sp[m * EMB + ee];
    v = s;
  }
  Wt[(size_t)k * G4 + n] = v;
}

// bias_obs[n] = b_ih+b_hh + W_ih[:, :128]@b_in + W_ih[:,128:]@b_sp  (permuted)
// bias_pred[n] = b_ih+b_hh + W_ih[:, :128]@b_in
__global__ void pack_bias_kernel(const float* __restrict__ W_ih,
                                 const float* __restrict__ b_in, const float* __restrict__ b_sp,
                                 const float* __restrict__ b_ih, const float* __restrict__ b_hh,
                                 float* __restrict__ bias_obs, float* __restrict__ bias_pred) {
  int gid = blockIdx.x * blockDim.x + threadIdx.x;  // 0..1023
  if (gid >= 2 * G4) return;
  int n = gid & 511, which = gid >> 9;
  int cg = n >> 3, q = n & 7, gate = q >> 1, e = q & 1;
  int j = gate * Hs + 2 * cg + e;
  float s = b_ih[j] + b_hh[j];
  for (int m = 0; m < 128; ++m) s += W_ih[j * 256 + m] * b_in[m];
  if (which == 0) {
    for (int m = 0; m < 128; ++m) s += W_ih[j * 256 + 128 + m] * b_sp[m];
    bias_obs[n] = s;
  } else {
    bias_pred[n] = s;
  }
}

// ---------------------------------------------------------------------------
// Social pooling precompute: pooled[b][t][32] = sum_n embed_table[cell(b,n,t)]
// One thread per (b,t). Reads neighbors exactly once, coalesced across t.
// ---------------------------------------------------------------------------
__global__ void pool_kernel(const float* __restrict__ obs, const float* __restrict__ nb,
                            const float* __restrict__ table, float* __restrict__ pooled) {
  __shared__ __align__(16) float tl[16][36];
  int tid = threadIdx.x;
  for (int i = tid; i < 16 * EMB; i += 256) tl[i >> 5][i & 31] = table[i];
  __syncthreads();
  int gid = blockIdx.x * 256 + tid;  // gid = b*8 + t
  int b = gid >> 3, t = gid & 7;
  float ox = obs[2 * (size_t)gid], oy = obs[2 * (size_t)gid + 1];
  float acc[EMB];
#pragma unroll
  for (int e = 0; e < EMB; ++e) acc[e] = 0.f;
  for (int n = 0; n < NBR; ++n) {
    size_t base = ((((size_t)b * NBR + n) * Tobs) + t) * 2;
    float rx = nb[base] - ox, ry = nb[base + 1] - oy;
    int ix = (int)floorf(rx + rx);  // floor(rel / 0.5)
    int iy = (int)floorf(ry + ry);
    ix = min(max(ix, -2), 1);
    iy = min(max(iy, -2), 1);
    int flat = (ix + 2) * 4 + (iy + 2);
    const float4* trow = (const float4*)(&tl[flat][0]);
#pragma unroll
    for (int e4 = 0; e4 < 8; ++e4) {
      float4 tv = trow[e4];
      acc[4 * e4 + 0] += tv.x;
      acc[4 * e4 + 1] += tv.y;
      acc[4 * e4 + 2] += tv.z;
      acc[4 * e4 + 3] += tv.w;
    }
  }
  float4* op = (float4*)(pooled + (size_t)gid * EMB);
#pragma unroll
  for (int e4 = 0; e4 < 8; ++e4)
    op[e4] = make_float4(acc[4 * e4 + 0], acc[4 * e4 + 1], acc[4 * e4 + 2], acc[4 * e4 + 3]);
}

// ---------------------------------------------------------------------------
// Main persistent-per-tile kernel: 32 batch rows/block, 20 recurrent steps.
// ---------------------------------------------------------------------------
__device__ __forceinline__ void gemm_tile(float acc[8][8], const float4* __restrict__ Wt4,
                                          const float (*xh)[KP], int kmax, int arow, int cg) {
#pragma unroll
  for (int r = 0; r < 8; ++r)
#pragma unroll
    for (int q = 0; q < 8; ++q) acc[r][q] = 0.f;
  const float4* bp = Wt4 + 2 * cg;
#pragma unroll 2
  for (int k = 0; k < kmax; ++k) {
    float4 b0 = bp[(size_t)k * 128];
    float4 b1 = bp[(size_t)k * 128 + 1];
    const float4* ap = (const float4*)(&xh[k][arow]);
    float4 a0 = ap[0];
    float4 a1 = ap[1];
    float av[8] = {a0.x, a0.y, a0.z, a0.w, a1.x, a1.y, a1.z, a1.w};
    float bv[8] = {b0.x, b0.y, b0.z, b0.w, b1.x, b1.y, b1.z, b1.w};
#pragma unroll
    for (int r = 0; r < 8; ++r)
#pragma unroll
      for (int q = 0; q < 8; ++q) acc[r][q] = fmaf(av[r], bv[q], acc[r][q]);
  }
}

__global__ __launch_bounds__(256, 2) void social_lstm_main(
    const float* __restrict__ obs, const float* __restrict__ Wt,
    const float* __restrict__ bias_obs, const float* __restrict__ bias_pred,
    const float* __restrict__ pooled, const float* __restrict__ W_out,
    const float* __restrict__ b_out, float* __restrict__ out) {
  __shared__ __align__(16) float xh[KOBS][KP];  // k-major input panel: rows 0..127 h,
                                                // 128..129 o_t/prev, 130..161 pooled
  const int tid = threadIdx.x;
  const int cg = tid & 63;    // column group: owns gate cols n = cg*8..cg*8+7
  const int rg = tid >> 6;    // row group: owns batch rows rg*8..rg*8+7
  const int arow = rg * 8;
  const int b0 = blockIdx.x * Mrows;
  const float4* Wt4 = (const float4*)Wt;

  for (int i = tid; i < KOBS * KP; i += 256) (&xh[0][0])[i] = 0.f;
  float creg[8][2];
#pragma unroll
  for (int r = 0; r < 8; ++r) { creg[r][0] = 0.f; creg[r][1] = 0.f; }
  __syncthreads();

  float acc[8][8];

  // lstm epilogue: gates (acc + bias) -> update c (regs), write h to xh rows 0..127
  auto epilogue = [&](const float* __restrict__ bias) {
    const float4* b4 = (const float4*)bias;
    float4 bb0 = b4[2 * cg], bb1 = b4[2 * cg + 1];
    float bq[8] = {bb0.x, bb0.y, bb0.z, bb0.w, bb1.x, bb1.y, bb1.z, bb1.w};
#pragma unroll
    for (int r = 0; r < 8; ++r) {
#pragma unroll
      for (int e = 0; e < 2; ++e) {
        float iv = sigm(acc[r][0 + e] + bq[0 + e]);
        float fv = sigm(acc[r][2 + e] + bq[2 + e]);
        float gv = tanhf(acc[r][4 + e] + bq[4 + e]);
        float ov = sigm(acc[r][6 + e] + bq[6 + e]);
        float cv = fv * creg[r][e] + iv * gv;
        creg[r][e] = cv;
        xh[2 * cg + e][arow + r] = ov * tanhf(cv);
      }
    }
  };

  // ---- observation phase ----
  for (int t = 0; t < Tobs; ++t) {
    if (tid < 64) {
      int row = tid >> 1, c2 = tid & 1;
      xh[128 + c2][row] = obs[((size_t)(b0 + row) * Tobs + t) * 2 + c2];
    }
    {
      int row = tid >> 3;
      int e0 = tid & 7;
#pragma unroll
      for (int i = 0; i < 4; ++i)
        xh[130 + e0 + 8 * i][row] =
            pooled[(((size_t)(b0 + row)) * Tobs + t) * EMB + e0 + 8 * i];
    }
    __syncthreads();
    gemm_tile(acc, Wt4, xh, KOBS, arow, cg);
    __syncthreads();
    epilogue(bias_obs);
  }

  // ---- transition: prev displacement = 0 ----
  if (tid < 64) {
    int row = tid >> 1, c2 = tid & 1;
    xh[128 + c2][row] = 0.f;
  }

  // ---- prediction phase ----
  for (int p = 0; p < PREDL; ++p) {
    __syncthreads();
    gemm_tile(acc, Wt4, xh, KPRED, arow, cg);
    __syncthreads();
    epilogue(bias_pred);
    __syncthreads();
    if (tid < 64) {
      int row = tid >> 1, j = tid & 1;
      float s = b_out[j];
      for (int hc = 0; hc < Hs; ++hc) s = fmaf(W_out[j * Hs + hc], xh[hc][row], s);
      out[((size_t)(b0 + row)) * (PREDL * 2) + p * 2 + j] = s;
      xh[128 + j][row] = s;  // prev displacement for next step
    }
  }
}

// ---------------------------------------------------------------------------
extern "C" void kernel_launch(void* const* d_in, const int* in_sizes, int n_in,
                              void* d_out, int out_size, void* d_ws, size_t ws_size,
                              hipStream_t stream) {
  const float* obs    = (const float*)d_in[0];
  const float* nbrs   = (const float*)d_in[1];
  const float* table  = (const float*)d_in[2];
  const float* W_in   = (const float*)d_in[3];
  const float* b_in   = (const float*)d_in[4];
  const float* W_sp   = (const float*)d_in[5];
  const float* b_sp   = (const float*)d_in[6];
  const float* W_ih   = (const float*)d_in[7];
  const float* W_hh   = (const float*)d_in[8];
  const float* b_ih   = (const float*)d_in[9];
  const float* b_hh   = (const float*)d_in[10];
  const float* W_out  = (const float*)d_in[11];
  const float* b_out  = (const float*)d_in[12];
  float* out = (float*)d_out;

  // Workspace layout (floats): Wt[162*512] | bias_obs[512] | bias_pred[512] | pooled[B*T*32]
  // Total = 82944 + 512 + 512 + 4194304 floats = ~16.4 MB
  float* ws        = (float*)d_ws;
  float* Wt        = ws;
  float* bias_obs  = ws + 82944;
  float* bias_pred = ws + 83456;
  float* pooled    = ws + 83968;

  pack_w_kernel<<<(KOBS * G4 + 255) / 256, 256, 0, stream>>>(W_ih, W_hh, W_in, W_sp, Wt);
  pack_bias_kernel<<<2, 512, 0, stream>>>(W_ih, b_in, b_sp, b_ih, b_hh, bias_obs, bias_pred);
  pool_kernel<<<(Bsz * Tobs) / 256, 256, 0, stream>>>(obs, nbrs, table, pooled);
  social_lstm_main<<<Bsz / Mrows, 256, 0, stream>>>(obs, Wt, bias_obs, bias_pred, pooled,
                                                    W_out, b_out, out);
}

// Round 2
// 249.197 us; speedup vs baseline: 3.5787x; 3.5787x over previous
//
#include <hip/hip_runtime.h>
#include <math.h>

typedef _Float16 f16;
typedef f16 f16x8 __attribute__((ext_vector_type(8)));
typedef float f32x4 __attribute__((ext_vector_type(4)));

#define Bsz   16384
#define Tobs  8
#define NBR   64
#define PREDL 12

// fast activations: v_exp_f32 + v_rcp_f32 (~1ulp each, negligible vs fp16 input rounding)
__device__ __forceinline__ float fast_sigm(float x) {
  float e = __builtin_amdgcn_exp2f(-1.44269504f * x);
  return __builtin_amdgcn_rcpf(1.f + e);
}
__device__ __forceinline__ float fast_tanh(float x) {
  float e = __builtin_amdgcn_exp2f(2.88539008f * x);   // e^(2x)
  return 1.f - 2.f * __builtin_amdgcn_rcpf(1.f + e);
}

// ---------------------------------------------------------------------------
// Column permutation: n' = w*64 + gate*16 + l  (w=wave 0..7, gate 0..3, l 0..15)
//   => j_orig = gate*128 + (w*16 + l)
// Wfrag layout [kt(5)][w(8)][nt=gate(4)][lane(64)][j(8)] fp16, B[k][n'] with
//   k = kt*32 + (lane>>4)*8 + j   (kt<4: W_hh; kt==4: W_isp = W_ih[:,128:]@W_sp)
// ---------------------------------------------------------------------------
__global__ void pack_w_kernel(const float* __restrict__ W_ih, const float* __restrict__ W_hh,
                              const float* __restrict__ W_sp, f16* __restrict__ Wfrag) {
  int gid = blockIdx.x * 256 + threadIdx.x;
  if (gid >= 5 * 8 * 4 * 64 * 8) return;
  int j  = gid & 7;
  int ln = (gid >> 3) & 63;
  int nt = (gid >> 9) & 3;
  int w  = (gid >> 11) & 7;
  int kt = gid >> 14;
  int l = ln & 15, q = ln >> 4;
  int k = kt * 32 + q * 8 + j;
  int jo = nt * 128 + w * 16 + l;   // original gate row
  float v;
  if (kt < 4) {
    v = W_hh[jo * 128 + k];
  } else {
    int kk = k - 128;  // emb index 0..31
    float s = 0.f;
    for (int m = 0; m < 128; ++m) s += W_ih[jo * 256 + 128 + m] * W_sp[m * 32 + kk];
    v = s;
  }
  Wfrag[gid] = (f16)v;
}

// biasO/biasP (permuted, 512 each) + W_io permuted (512x2):
// biasO = b_ih+b_hh + W_ih[:,:128]@b_in + W_ih[:,128:]@b_sp ; biasP drops b_sp term
__global__ void pack_misc_kernel(const float* __restrict__ W_ih, const float* __restrict__ W_in,
                                 const float* __restrict__ b_in, const float* __restrict__ b_sp,
                                 const float* __restrict__ b_ih, const float* __restrict__ b_hh,
                                 float* __restrict__ biasO, float* __restrict__ biasP,
                                 float* __restrict__ wio) {
  int gid = blockIdx.x * 256 + threadIdx.x;
  if (gid >= 2048) return;
  if (gid < 1024) {
    int n = gid & 511;
    int w = n >> 6, nt = (n >> 4) & 3, l = n & 15;
    int jo = nt * 128 + w * 16 + l;
    float s = b_ih[jo] + b_hh[jo];
    for (int m = 0; m < 128; ++m) s += W_ih[jo * 256 + m] * b_in[m];
    if (gid < 512) {
      for (int m = 0; m < 128; ++m) s += W_ih[jo * 256 + 128 + m] * b_sp[m];
      biasO[n] = s;
    } else {
      biasP[n] = s;
    }
  } else {
    int idx = gid - 1024;
    int n = idx >> 1, c = idx & 1;
    int w = n >> 6, nt = (n >> 4) & 3, l = n & 15;
    int jo = nt * 128 + w * 16 + l;
    float s = 0.f;
    for (int m = 0; m < 128; ++m) s += W_ih[jo * 256 + m] * W_in[m * 2 + c];
    wio[n * 2 + c] = s;
  }
}

// ---------------------------------------------------------------------------
// Social pooling: pooled[b][t][32] (fp16) = sum_n embed_table[cell]
// ---------------------------------------------------------------------------
__global__ void pool_kernel(const float* __restrict__ obs, const float* __restrict__ nb,
                            const float* __restrict__ table, f16* __restrict__ pooled) {
  __shared__ __align__(16) float tl[16][36];
  int tid = threadIdx.x;
  for (int i = tid; i < 16 * 32; i += 256) tl[i >> 5][i & 31] = table[i];
  __syncthreads();
  int gid = blockIdx.x * 256 + tid;  // gid = b*8 + t
  int b = gid >> 3, t = gid & 7;
  float ox = obs[2 * (size_t)gid], oy = obs[2 * (size_t)gid + 1];
  float acc[32];
#pragma unroll
  for (int e = 0; e < 32; ++e) acc[e] = 0.f;
  for (int n = 0; n < NBR; ++n) {
    size_t base = ((((size_t)b * NBR + n) * Tobs) + t) * 2;
    float rx = nb[base] - ox, ry = nb[base + 1] - oy;
    int ix = (int)floorf(rx + rx);
    int iy = (int)floorf(ry + ry);
    ix = min(max(ix, -2), 1);
    iy = min(max(iy, -2), 1);
    int flat = (ix + 2) * 4 + (iy + 2);
    const float4* trow = (const float4*)(&tl[flat][0]);
#pragma unroll
    for (int e4 = 0; e4 < 8; ++e4) {
      float4 tv = trow[e4];
      acc[4 * e4 + 0] += tv.x;
      acc[4 * e4 + 1] += tv.y;
      acc[4 * e4 + 2] += tv.z;
      acc[4 * e4 + 3] += tv.w;
    }
  }
  f16x8* op = (f16x8*)(pooled + (size_t)gid * 32);
#pragma unroll
  for (int v8 = 0; v8 < 4; ++v8) {
    f16x8 h;
#pragma unroll
    for (int e = 0; e < 8; ++e) h[e] = (f16)acc[v8 * 8 + e];
    op[v8] = h;
  }
}

// ---------------------------------------------------------------------------
// Main: 64 batch rows/block, 512 threads (8 waves), MFMA fp16 K-loop,
// W_hh fragments persistent in VGPRs, double-buffered LDS h-panel.
// ---------------------------------------------------------------------------
__global__ __launch_bounds__(512, 2) void social_lstm_main(
    const float* __restrict__ obs, const f16* __restrict__ Wfrag,
    const float* __restrict__ biasO, const float* __restrict__ biasP,
    const float* __restrict__ wio, const f16* __restrict__ pooled,
    const float* __restrict__ W_out, const float* __restrict__ b_out,
    float* __restrict__ out) {
  // A-panel: [buf(2)][kt(4)][mt(4)][lane(64)][j(8)] fp16 = 32 KB
  __shared__ __align__(16) f16 Abuf[2 * 4 * 4 * 64 * 8];
  __shared__ float xybuf[2][64][2];
  __shared__ float red[2][64][4];
  __shared__ float sb[2048];  // biasO 512 | biasP 512 | wio 1024

  const int tid = threadIdx.x;
  const int w = tid >> 6, ln = tid & 63;
  const int q = ln >> 4, l = ln & 15;
  const int b0 = blockIdx.x * 64;

  for (int i = tid; i < 2048; i += 512)
    sb[i] = (i < 512) ? biasO[i] : (i < 1024 ? biasP[i - 512] : wio[i - 1024]);
  for (int i = tid; i < 4096; i += 512) ((uint32_t*)Abuf)[i] = 0u;  // zero buf 0
  if (tid < 128) {  // stage o_0 into xybuf[0]
    int row = tid >> 1, c = tid & 1;
    xybuf[0][row][c] = obs[((size_t)(b0 + row) * Tobs + 0) * 2 + c];
  }

  // persistent B fragments: W_hh
  f16x8 Bh[4][4];
#pragma unroll
  for (int kt = 0; kt < 4; ++kt)
#pragma unroll
    for (int nt = 0; nt < 4; ++nt)
      Bh[kt][nt] = *(const f16x8*)(Wfrag + (size_t)((((kt * 8 + w) * 4 + nt) * 64 + ln) * 8));

  float creg[16];
#pragma unroll
  for (int i = 0; i < 16; ++i) creg[i] = 0.f;

  // epilogue constants
  const int hc = w * 16 + l;
  const int aw_kt = hc >> 5;
  const int aw_quad = (hc >> 3) & 3;
  const int aw_j = l & 7;

  __syncthreads();  // sb visible
  float bOr[4], bPr[4], wxr[4], wyr[4];
#pragma unroll
  for (int g = 0; g < 4; ++g) {
    int col = w * 64 + g * 16 + l;
    bOr[g] = sb[col];
    bPr[g] = sb[512 + col];
    wxr[g] = sb[1024 + col * 2];
    wyr[g] = sb[1024 + col * 2 + 1];
  }

  f32x4 acc[4][4];

#define EPILOGUE(BIAS, RB, WB)                                                     \
  {                                                                                \
    _Pragma("unroll") for (int mt = 0; mt < 4; ++mt) {                             \
      _Pragma("unroll") for (int reg = 0; reg < 4; ++reg) {                        \
        int m = mt * 16 + q * 4 + reg;                                             \
        float px = xybuf[RB][m][0], py = xybuf[RB][m][1];                          \
        float p0 = acc[mt][0][reg] + bOrP0 + wxr[0] * px + wyr[0] * py;            \
        float p1 = acc[mt][1][reg] + bOrP1 + wxr[1] * px + wyr[1] * py;            \
        float p2 = acc[mt][2][reg] + bOrP2 + wxr[2] * px + wyr[2] * py;            \
        float p3 = acc[mt][3][reg] + bOrP3 + wxr[3] * px + wyr[3] * py;            \
        float iv = fast_sigm(p0), fv = fast_sigm(p1);                              \
        float gv = fast_tanh(p2), ov = fast_sigm(p3);                              \
        int ci = mt * 4 + reg;                                                     \
        float c2 = fv * creg[ci] + iv * gv;                                        \
        creg[ci] = c2;                                                             \
        float hv = ov * fast_tanh(c2);                                             \
        Abuf[((((WB)*4 + aw_kt) * 4 + mt) * 64 + ((q * 4 + reg) + 16 * aw_quad)) * \
                 8 + aw_j] = (f16)hv;                                              \
      }                                                                            \
    }                                                                              \
  }

  // ---------------- observation phase: 1 barrier per step ----------------
  for (int t = 0; t < Tobs; ++t) {
    const int rb = t & 1, wb = rb ^ 1;
    __syncthreads();  // prev epilogue writes + xy stage visible
    if (tid < 128) {  // stage xy for step t+1 (zeros for first pred step)
      int row = tid >> 1, c = tid & 1;
      float v = (t < 7) ? obs[((size_t)(b0 + row) * Tobs + (t + 1)) * 2 + c] : 0.f;
      xybuf[wb][row][c] = v;
    }
    // pooled A-fragments (global) + W_isp B-fragments (global, kt=4)
    f16x8 Ap[4], Bsp[4];
#pragma unroll
    for (int mt = 0; mt < 4; ++mt)
      Ap[mt] = *(const f16x8*)(pooled +
                               (((size_t)(b0 + mt * 16 + l) * Tobs) + t) * 32 + q * 8);
#pragma unroll
    for (int nt = 0; nt < 4; ++nt)
      Bsp[nt] = *(const f16x8*)(Wfrag + (size_t)((((4 * 8 + w) * 4 + nt) * 64 + ln) * 8));
#pragma unroll
    for (int mt = 0; mt < 4; ++mt)
#pragma unroll
      for (int nt = 0; nt < 4; ++nt)
        acc[mt][nt] = (f32x4){0.f, 0.f, 0.f, 0.f};
#pragma unroll
    for (int mt = 0; mt < 4; ++mt)
#pragma unroll
      for (int nt = 0; nt < 4; ++nt)
        acc[mt][nt] = __builtin_amdgcn_mfma_f32_16x16x32_f16(Ap[mt], Bsp[nt], acc[mt][nt], 0, 0, 0);
#pragma unroll
    for (int kt = 0; kt < 4; ++kt) {
      f16x8 Af[4];
#pragma unroll
      for (int mt = 0; mt < 4; ++mt)
        Af[mt] = *(const f16x8*)(&Abuf[(((rb * 4 + kt) * 4 + mt) * 64 + ln) * 8]);
#pragma unroll
      for (int mt = 0; mt < 4; ++mt)
#pragma unroll
        for (int nt = 0; nt < 4; ++nt)
          acc[mt][nt] = __builtin_amdgcn_mfma_f32_16x16x32_f16(Af[mt], Bh[kt][nt], acc[mt][nt], 0, 0, 0);
    }
#define bOrP0 bOr[0]
#define bOrP1 bOr[1]
#define bOrP2 bOr[2]
#define bOrP3 bOr[3]
    EPILOGUE(, rb, wb)
#undef bOrP0
#undef bOrP1
#undef bOrP2
#undef bOrP3
  }

  // ---------------- prediction phase ----------------
  for (int p = 0; p < PREDL; ++p) {
    const int s = Tobs + p;
    const int rb = s & 1, wb = rb ^ 1;
    __syncthreads();  // barrier A
#pragma unroll
    for (int mt = 0; mt < 4; ++mt)
#pragma unroll
      for (int nt = 0; nt < 4; ++nt)
        acc[mt][nt] = (f32x4){0.f, 0.f, 0.f, 0.f};
#pragma unroll
    for (int kt = 0; kt < 4; ++kt) {
      f16x8 Af[4];
#pragma unroll
      for (int mt = 0; mt < 4; ++mt)
        Af[mt] = *(const f16x8*)(&Abuf[(((rb * 4 + kt) * 4 + mt) * 64 + ln) * 8]);
#pragma unroll
      for (int mt = 0; mt < 4; ++mt)
#pragma unroll
        for (int nt = 0; nt < 4; ++nt)
          acc[mt][nt] = __builtin_amdgcn_mfma_f32_16x16x32_f16(Af[mt], Bh[kt][nt], acc[mt][nt], 0, 0, 0);
    }
#define bOrP0 bPr[0]
#define bOrP1 bPr[1]
#define bOrP2 bPr[2]
#define bOrP3 bPr[3]
    EPILOGUE(, rb, wb)
#undef bOrP0
#undef bOrP1
#undef bOrP2
#undef bOrP3
    __syncthreads();  // barrier B: h_p visible
    {                 // output partials: disp = h @ W_out^T
      int row = tid & 63, jj = (tid >> 6) & 1, seg = tid >> 7;
      float sacc = 0.f;
#pragma unroll
      for (int quad = 0; quad < 4; ++quad) {
        f16x8 h8 = *(const f16x8*)(
            &Abuf[(((wb * 4 + seg) * 4 + (row >> 4)) * 64 + ((row & 15) + 16 * quad)) * 8]);
        const float4* wo = (const float4*)(W_out + jj * 128 + seg * 32 + quad * 8);
        float4 w0 = wo[0], w1 = wo[1];
        sacc += w0.x * (float)h8[0] + w0.y * (float)h8[1] + w0.z * (float)h8[2] +
                w0.w * (float)h8[3] + w1.x * (float)h8[4] + w1.y * (float)h8[5] +
                w1.z * (float)h8[6] + w1.w * (float)h8[7];
      }
      red[jj][row][seg] = sacc;
    }
    __syncthreads();  // barrier C
    if (tid < 128) {
      int row = tid >> 1, jj = tid & 1;
      float d = b_out[jj] + red[jj][row][0] + red[jj][row][1] + red[jj][row][2] + red[jj][row][3];
      out[((size_t)(b0 + row)) * (PREDL * 2) + p * 2 + jj] = d;
      xybuf[wb][row][jj] = d;  // prev-disp for next step
    }
  }
}

// ---------------------------------------------------------------------------
extern "C" void kernel_launch(void* const* d_in, const int* in_sizes, int n_in,
                              void* d_out, int out_size, void* d_ws, size_t ws_size,
                              hipStream_t stream) {
  const float* obs   = (const float*)d_in[0];
  const float* nbrs  = (const float*)d_in[1];
  const float* table = (const float*)d_in[2];
  const float* W_in  = (const float*)d_in[3];
  const float* b_in  = (const float*)d_in[4];
  const float* W_sp  = (const float*)d_in[5];
  const float* b_sp  = (const float*)d_in[6];
  const float* W_ih  = (const float*)d_in[7];
  const float* W_hh  = (const float*)d_in[8];
  const float* b_ih  = (const float*)d_in[9];
  const float* b_hh  = (const float*)d_in[10];
  const float* W_out = (const float*)d_in[11];
  const float* b_out = (const float*)d_in[12];
  float* out = (float*)d_out;

  // ws layout (bytes): Wfrag f16[81920] @0 | biasO f32[512] @163840 |
  //                    biasP @165888 | wio f32[1024] @167936 | pooled f16 @172032
  char* ws = (char*)d_ws;
  f16*   Wfrag  = (f16*)(ws);
  float* biasO  = (float*)(ws + 163840);
  float* biasP  = (float*)(ws + 165888);
  float* wio    = (float*)(ws + 167936);
  f16*   pooled = (f16*)(ws + 172032);

  pack_w_kernel<<<320, 256, 0, stream>>>(W_ih, W_hh, W_sp, Wfrag);
  pack_misc_kernel<<<8, 256, 0, stream>>>(W_ih, W_in, b_in, b_sp, b_ih, b_hh, biasO, biasP, wio);
  pool_kernel<<<(Bsz * Tobs) / 256, 256, 0, stream>>>(obs, nbrs, table, pooled);
  social_lstm_main<<<Bsz / 64, 512, 0, stream>>>(obs, Wfrag, biasO, biasP, wio, pooled,
                                                 W_out, b_out, out);
}